// Round 2
// baseline (279.313 us; speedup 1.0000x reference)
//
#include <hip/hip_runtime.h>
#include <hip/hip_bf16.h>

#define B_ 4
#define C_ 128
#define H_ 96
#define W_ 96
#define MD 20
#define K41 41
#define OH 48
#define OW 48
#define TSZ ((size_t)B_*H_*W_*C_)   // elements per transposed tensor

using bf16x8 = __attribute__((ext_vector_type(8))) short;
using f32x4  = __attribute__((ext_vector_type(4))) float;

// ---------------------------------------------------------------------------
// Pre-pass: [B][C][H][W] fp32  ->  [B][H][W][C] bf16  (LDS-tiled transpose)
// ---------------------------------------------------------------------------
__global__ __launch_bounds__(256) void transpose_convert(
    const float* __restrict__ src, __hip_bfloat16* __restrict__ dst) {
    __shared__ float tile[32][W_ + 1];          // +1 pad: conflict-free col reads
    const int y = blockIdx.x, cb = blockIdx.y, b = blockIdx.z;
    const int tid = threadIdx.x;
    for (int idx = tid; idx < 32 * W_; idx += 256) {
        int ci = idx / W_, x = idx - ci * W_;
        tile[ci][x] = src[(((size_t)b * C_ + cb * 32 + ci) * H_ + y) * W_ + x];
    }
    __syncthreads();
    for (int idx = tid; idx < 32 * W_; idx += 256) {
        int x = idx >> 5, ci = idx & 31;
        dst[(((size_t)b * H_ + y) * W_ + x) * C_ + cb * 32 + ci] =
            __float2bfloat16(tile[ci][x]);
    }
}

// ---------------------------------------------------------------------------
// Main: one block per (j, oy, b). 6 waves; wave w owns m-tile (x in [16w,16w+16)).
// Banded Gram via mfma_f32_16x16x32_bf16, pooled epilogue.
// ---------------------------------------------------------------------------
__global__ __launch_bounds__(384) void corr_mfma(
    const __hip_bfloat16* __restrict__ x1t,
    const __hip_bfloat16* __restrict__ x2t,
    float* __restrict__ out) {
    const int j = blockIdx.x, oy = blockIdx.y, b = blockIdx.z;
    const int tid = threadIdx.x, wave = tid >> 6, lane = tid & 63;
    const int y1 = oy * 2;

    __shared__ __hip_bfloat16 x2s[W_ * C_];     // one x2 row, XOR-swizzled   (24576 B)
    __shared__ float G[96 * 100];               // Gram band, stride 100      (38400 B)

    // A fragments (x1, both pooling rows, all 4 K-steps) -> registers
    const int m  = (wave << 4) | (lane & 15);   // x position (A row)
    const int c0 = (lane >> 4) << 3;            // k-group base channel
    bf16x8 a[2][4];
    const __hip_bfloat16* x1base =
        x1t + (((size_t)b * H_ + y1) * W_ + m) * C_ + c0;
#pragma unroll
    for (int p = 0; p < 2; ++p)
#pragma unroll
        for (int k = 0; k < 4; ++k)
            a[p][k] = *(const bf16x8*)(x1base + (size_t)p * (W_ * C_) + k * 32);

    float racc[6] = {0.f, 0.f, 0.f, 0.f, 0.f, 0.f};

    const int ntlo = (wave - 2 < 0) ? 0 : wave - 2;
    const int nthi = (wave + 2 > 5) ? 5 : wave + 2;
    const int mrow = (wave << 4) | ((lane >> 4) << 2);

    for (int p = 0; p < 2; ++p) {
        // ---- stage x2 row r (zero-fill if out of bounds) ----
        const int r = y1 + p + j - MD;
        const bool valid = (r >= 0) && (r < H_);
        const __hip_bfloat16* src = x2t + ((size_t)b * H_ + (valid ? r : 0)) * W_ * C_;
#pragma unroll
        for (int it = 0; it < 4; ++it) {
            int elem = (it * 384 + tid) * 8;            // 8 bf16 per 16B chunk
            int u    = elem >> 7;                       // x2 column (row of tile)
            int byte = (elem << 1) ^ ((u & 7) << 4);    // XOR swizzle
            bf16x8 v = {0, 0, 0, 0, 0, 0, 0, 0};
            if (valid) v = *(const bf16x8*)(src + elem);
            *(bf16x8*)((char*)x2s + byte) = v;
        }
        __syncthreads();

        // ---- banded Gram: D[m][u] = sum_c x1[m][c] * x2[u][c] ----
        for (int nt = ntlo; nt <= nthi; ++nt) {
            const int u = (nt << 4) | (lane & 15);      // B col = u
            f32x4 acc = {0.f, 0.f, 0.f, 0.f};
#pragma unroll
            for (int k = 0; k < 4; ++k) {
                int byte = ((u * C_ + k * 32 + c0) << 1) ^ ((u & 7) << 4);
                bf16x8 bf = *(const bf16x8*)((const char*)x2s + byte);
                acc = __builtin_amdgcn_mfma_f32_16x16x32_bf16(a[p][k], bf, acc, 0, 0, 0);
            }
#pragma unroll
            for (int reg = 0; reg < 4; ++reg)
                G[(mrow + reg) * 100 + u] = acc[reg];   // row=(lane>>4)*4+reg, col=lane&15
        }
        __syncthreads();

        // ---- pooled partial epilogue for this p ----
#pragma unroll
        for (int s = 0; s < 6; ++s) {
            int idx = tid + s * 384;
            if (idx < K41 * OW) {
                int i = idx / OW, ox = idx - i * OW;
                int u = 2 * ox + i - MD;
                float v = 0.f;
                if (u >= 0 && u < W_)         v += G[(2 * ox) * 100 + u];
                if (u + 1 >= 0 && u + 1 < W_) v += G[(2 * ox + 1) * 100 + u + 1];
                racc[s] += v;
            }
        }
        __syncthreads();
    }

    // ---- store: out[b][i*41+j][oy][ox] ----
#pragma unroll
    for (int s = 0; s < 6; ++s) {
        int idx = tid + s * 384;
        if (idx < K41 * OW) {
            int i = idx / OW, ox = idx - i * OW;
            out[(((size_t)b * (K41 * K41) + i * K41 + j) * OH + oy) * OW + ox] =
                racc[s] * (1.f / 512.f);
        }
    }
}

// ---------------------------------------------------------------------------
// Fallback (ws too small): naive fp32, one thread per output
// ---------------------------------------------------------------------------
__global__ void corr_naive(const float* __restrict__ x1, const float* __restrict__ x2,
                           float* __restrict__ out, int total) {
    int idx = blockIdx.x * 256 + threadIdx.x;
    if (idx >= total) return;
    int ox = idx % OW;
    int t  = idx / OW;
    int oy = t % OH;  t /= OH;
    int d  = t % (K41 * K41);
    int b  = t / (K41 * K41);
    int i = d / K41, jj = d - i * K41;
    float sum = 0.f;
    for (int p = 0; p < 2; ++p)
        for (int q = 0; q < 2; ++q) {
            int y = 2 * oy + p, x = 2 * ox + q;
            int r = y + jj - MD, u = x + i - MD;
            if (r < 0 || r >= H_ || u < 0 || u >= W_) continue;
            const float* p1 = x1 + ((size_t)b * C_ * H_ + y) * W_ + x;
            const float* p2 = x2 + ((size_t)b * C_ * H_ + r) * W_ + u;
            for (int c = 0; c < C_; ++c)
                sum += p1[(size_t)c * H_ * W_] * p2[(size_t)c * H_ * W_];
        }
    out[idx] = sum * (1.f / 512.f);
}

extern "C" void kernel_launch(void* const* d_in, const int* in_sizes, int n_in,
                              void* d_out, int out_size, void* d_ws, size_t ws_size,
                              hipStream_t stream) {
    const float* x1 = (const float*)d_in[0];
    const float* x2 = (const float*)d_in[1];
    float* out = (float*)d_out;

    const size_t need = 2 * TSZ * sizeof(__hip_bfloat16);   // 18,874,368 B
    if (ws_size >= need && d_ws != nullptr) {
        __hip_bfloat16* x1t = (__hip_bfloat16*)d_ws;
        __hip_bfloat16* x2t = x1t + TSZ;
        transpose_convert<<<dim3(H_, 4, B_), 256, 0, stream>>>(x1, x1t);
        transpose_convert<<<dim3(H_, 4, B_), 256, 0, stream>>>(x2, x2t);
        corr_mfma<<<dim3(K41, OH, B_), 384, 0, stream>>>(x1t, x2t, out);
    } else {
        int total = B_ * K41 * K41 * OH * OW;
        corr_naive<<<(total + 255) / 256, 256, 0, stream>>>(x1, x2, out, total);
    }
}

// Round 3
// 188.612 us; speedup vs baseline: 1.4809x; 1.4809x over previous
//
#include <hip/hip_runtime.h>
#include <hip/hip_bf16.h>

#define B_ 4
#define C_ 128
#define H_ 96
#define W_ 96
#define MD 20
#define K41 41
#define OH 48
#define OW 48
#define HW_ (H_ * W_)
#define TSZ ((size_t)B_ * H_ * W_ * C_)   // elements per transposed tensor

using bf16x8 = __attribute__((ext_vector_type(8))) short;
using f32x4  = __attribute__((ext_vector_type(4))) float;

__device__ __forceinline__ unsigned short f2bf(float f) {   // RNE fp32->bf16
    unsigned int u = __float_as_uint(f);
    return (unsigned short)((u + 0x7fff + ((u >> 16) & 1)) >> 16);
}

__device__ __forceinline__ void async_load16(const void* g, void* l) {
    __builtin_amdgcn_global_load_lds(
        (const __attribute__((address_space(1))) unsigned int*)g,
        (__attribute__((address_space(3))) unsigned int*)l, 16, 0, 0);
}

// ---------------------------------------------------------------------------
// Fused transpose+convert for BOTH tensors: [B][C][H][W] f32 -> [B][H][W][C] bf16
// grid (H_, 1, 2*B_), block 256. Coalesced strided reads, 16B packed stores.
// ---------------------------------------------------------------------------
__global__ __launch_bounds__(256) void transpose_convert(
    const float* __restrict__ x1, const float* __restrict__ x2,
    short* __restrict__ x1t, short* __restrict__ x2t) {
    const int y  = blockIdx.x;
    const int zb = blockIdx.z;
    const int b  = zb & 3;
    const float* src = (zb & 4 ? x2 : x1) + (size_t)b * C_ * HW_ + (size_t)y * W_;
    short* dst = (zb & 4 ? x2t : x1t) + ((size_t)b * H_ + y) * W_ * C_;
    const int tid = threadIdx.x;
#pragma unroll
    for (int t = 0; t < 6; ++t) {
        int idx = t * 256 + tid;            // [0, 1536): 16 cgq x 96 x
        int cgq = idx / 96;
        int x   = idx - cgq * 96;
        const float* s0 = src + (size_t)(cgq * 8) * HW_ + x;
        bf16x8 pk;
#pragma unroll
        for (int e = 0; e < 8; ++e)
            pk[e] = (short)f2bf(s0[(size_t)e * HW_]);
        *(bf16x8*)(dst + x * C_ + cgq * 8) = pk;
    }
}

// ---------------------------------------------------------------------------
// Main: block per (j, oy, b). 6 waves; wave w owns x in [16w,16w+16) and
// ox in [8w, 8w+8). Per-wave Gram band (4 unaligned 16-wide tiles) + per-wave
// pooled epilogue (no cross-wave barriers between MFMA and epilogue).
// ---------------------------------------------------------------------------
__global__ __launch_bounds__(384, 4) void corr_mfma(
    const short* __restrict__ x1t, const short* __restrict__ x2t,
    float* __restrict__ out) {
    const int j = blockIdx.x, oy = blockIdx.y, b = blockIdx.z;
    const int tid = threadIdx.x, wv = tid >> 6, lane = tid & 63;
    const int y1 = oy * 2;

    __shared__ short x2s[W_ * C_];          // one x2 row, XOR-swizzled (24576 B)
    __shared__ float G[6][16][67];          // per-wave pooled band     (25728 B)

    const int ul    = lane & 15;
    const int hi    = lane >> 4;
    const int m     = (wv << 4) | ul;       // x position (A row)
    const int c0b   = hi << 4;              // byte offset of k-group base channel
    const int mrow4 = hi << 2;

    // A fragments (x1 rows y1, y1+1; 4 K-steps) -> registers
    bf16x8 a[2][4];
    const short* x1b = x1t + (((size_t)b * H_ + y1) * W_ + m) * C_ + (hi << 3);
#pragma unroll
    for (int p = 0; p < 2; ++p)
#pragma unroll
        for (int k = 0; k < 4; ++k)
            a[p][k] = *(const bf16x8*)(x1b + p * (W_ * C_) + k * 32);

    float racc[6] = {0.f, 0.f, 0.f, 0.f, 0.f, 0.f};
    const int ubase = (wv << 4) - 24;       // band origin (w-independent cols)

    for (int p = 0; p < 2; ++p) {
        if (p) __syncthreads();             // all waves done reading x2s
        const int r = y1 + p + j - MD;
        const bool valid = (r >= 0) && (r < H_);
        if (valid) {
            // linear LDS dest + inverse-swizzled global source (involution)
            const char* srcb = (const char*)(x2t + ((size_t)b * H_ + r) * W_ * C_);
#pragma unroll
            for (int t = 0; t < 4; ++t) {
                const int basei = (t * 6 + wv) << 10;   // wave-uniform LDS base
                const int d  = basei | (lane << 4);
                const int so = d ^ (((d >> 8) & 7) << 4);
                async_load16(srcb + so, (char*)x2s + basei);
            }
        } else {
            bf16x8 z = {0, 0, 0, 0, 0, 0, 0, 0};
#pragma unroll
            for (int t = 0; t < 4; ++t)
                *(bf16x8*)((char*)x2s + ((t * 384 + tid) << 4)) = z;
        }
        __syncthreads();                    // drains vmcnt (global_load_lds)

        // ---- banded Gram: 4 unaligned tiles covering u in [16w-24, 16w+40) ----
#pragma unroll
        for (int nt = 0; nt < 4; ++nt) {
            int u  = ubase + (nt << 4) + ul;
            int ur = u < 0 ? 0 : (u > 95 ? 95 : u);     // clamp (garbage cols never read)
            f32x4 acc = {0.f, 0.f, 0.f, 0.f};
#pragma unroll
            for (int k = 0; k < 4; ++k) {
                int byte = ((ur << 8) + (k << 6) + c0b) ^ ((ur & 7) << 4);
                bf16x8 bfr = *(const bf16x8*)((const char*)x2s + byte);
                acc = __builtin_amdgcn_mfma_f32_16x16x32_bf16(a[p][k], bfr, acc, 0, 0, 0);
            }
            int col = (nt << 4) + ul;
#pragma unroll
            for (int reg = 0; reg < 4; ++reg)
                G[wv][mrow4 + reg][col] = acc[reg];
        }

        // ---- per-wave pooled epilogue (own G slice; no barrier) ----
#pragma unroll
        for (int s = 0; s < 6; ++s) {
            int e = lane + s * 64;
            if (e < 328) {
                int i = e >> 3, oxl = e & 7;
                int col = 2 * oxl + i + 4;              // in [4,58], w-independent
                int u = (wv << 4) + col - 24;
                float v = 0.f;
                if (u >= 0 && u < 96)           v += G[wv][2 * oxl][col];
                if (u + 1 >= 0 && u + 1 < 96)   v += G[wv][2 * oxl + 1][col + 1];
                racc[s] += v;
            }
        }
    }

    // ---- store: out[b][i*41+j][oy][8w+oxl] ----
    const int ox0 = wv << 3;
#pragma unroll
    for (int s = 0; s < 6; ++s) {
        int e = lane + s * 64;
        if (e < 328) {
            int i = e >> 3, oxl = e & 7;
            out[(((size_t)b * (K41 * K41) + i * K41 + j) * OH + oy) * OW + ox0 + oxl] =
                racc[s] * (1.f / 512.f);
        }
    }
}

// ---------------------------------------------------------------------------
// Fallback (ws too small): naive fp32, one thread per output
// ---------------------------------------------------------------------------
__global__ void corr_naive(const float* __restrict__ x1, const float* __restrict__ x2,
                           float* __restrict__ out, int total) {
    int idx = blockIdx.x * 256 + threadIdx.x;
    if (idx >= total) return;
    int ox = idx % OW;
    int t  = idx / OW;
    int oy = t % OH;  t /= OH;
    int d  = t % (K41 * K41);
    int b  = t / (K41 * K41);
    int i = d / K41, jj = d - i * K41;
    float sum = 0.f;
    for (int p = 0; p < 2; ++p)
        for (int q = 0; q < 2; ++q) {
            int y = 2 * oy + p, x = 2 * ox + q;
            int r = y + jj - MD, u = x + i - MD;
            if (r < 0 || r >= H_ || u < 0 || u >= W_) continue;
            const float* p1 = x1 + ((size_t)b * C_ * H_ + y) * W_ + x;
            const float* p2 = x2 + ((size_t)b * C_ * H_ + r) * W_ + u;
            for (int c = 0; c < C_; ++c)
                sum += p1[(size_t)c * HW_] * p2[(size_t)c * HW_];
        }
    out[idx] = sum * (1.f / 512.f);
}

extern "C" void kernel_launch(void* const* d_in, const int* in_sizes, int n_in,
                              void* d_out, int out_size, void* d_ws, size_t ws_size,
                              hipStream_t stream) {
    const float* x1 = (const float*)d_in[0];
    const float* x2 = (const float*)d_in[1];
    float* out = (float*)d_out;

    const size_t need = 2 * TSZ * sizeof(short);    // 18,874,368 B
    if (ws_size >= need && d_ws != nullptr) {
        short* x1t = (short*)d_ws;
        short* x2t = x1t + TSZ;
        transpose_convert<<<dim3(H_, 1, 2 * B_), 256, 0, stream>>>(x1, x2, x1t, x2t);
        corr_mfma<<<dim3(K41, OH, B_), 384, 0, stream>>>(x1t, x2t, out);
    } else {
        int total = B_ * K41 * K41 * OH * OW;
        corr_naive<<<(total + 255) / 256, 256, 0, stream>>>(x1, x2, out, total);
    }
}